// Round 1
// baseline (304.201 us; speedup 1.0000x reference)
//
#include <hip/hip_runtime.h>

typedef __bf16 bf16_t;
typedef __bf16 bf16x4_t __attribute__((ext_vector_type(4)));
typedef __bf16 bf16x8_t __attribute__((ext_vector_type(8)));
typedef float f32x16_t __attribute__((ext_vector_type(16)));

// ---------------------------------------------------------------------------
// Repack weight (oc, ic, ky, kx) fp32 -> bf16 in MFMA B-fragment order:
//   frag f = (((t*2+hk)*4 + kc)*2 + nt)*2 + wc     (288*... total 288 frags)
//   within frag: lane*8 + e  (lane 0..63, e 0..7)
//   lane maps to: oc = wc*64 + nt*32 + (lane&31); ic = (hk*8 + kc*2 + (lane>>5))*8 + e
// Each wave's fragment load is then a single contiguous, coalesced 1 KB read.
// ---------------------------------------------------------------------------
__global__ __launch_bounds__(256) void repack_kernel(const float* __restrict__ w,
                                                     bf16_t* __restrict__ wt2) {
  int o = blockIdx.x * 256 + threadIdx.x;  // 9*128*128 = 147456 exact
  int e = o & 7;
  int lane = (o >> 3) & 63;
  int f = o >> 9;
  int wc = f & 1;
  int nt = (f >> 1) & 1;
  int kc = (f >> 2) & 3;
  int hk = (f >> 4) & 1;
  int t = f >> 5;
  int oc = wc * 64 + nt * 32 + (lane & 31);
  int ic = (hk * 8 + kc * 2 + (lane >> 5)) * 8 + e;
  wt2[o] = (bf16_t)w[((size_t)oc * 128 + ic) * 9 + t];
}

// ---------------------------------------------------------------------------
// DWT: in fp32 (B,32,2h,2w) -> sub bf16 NHWC (B,h,w,128) ci=4c+q, ll fp32 (B,32,h,w)
// block: 256 thr = 64 j-lanes x 4 c-groups; one (b, i, 64-j chunk) per block
// ---------------------------------------------------------------------------
__global__ __launch_bounds__(256) void dwt_kernel(const float* __restrict__ in,
                                                  bf16_t* __restrict__ sub,
                                                  float* __restrict__ llout,
                                                  int h, int w) {
  __shared__ __align__(16) bf16_t lds[64 * 132];  // stride 132 (264B, ~2-way)
  const int bi = blockIdx.z;
  const int i = blockIdx.y;
  const int j0 = blockIdx.x * 64;
  const int tid = threadIdx.x;
  const int j = tid & 63;
  const int cg = tid >> 6;
  const int jg = j0 + j;
  const bool jok = jg < w;
  const int H2 = h * 2, W2 = w * 2;
  for (int c = cg; c < 32; c += 4) {
    float va = 0.f, vb = 0.f, vc = 0.f, vd = 0.f;
    if (jok) {
      const float2* p0 = (const float2*)(in + ((size_t)(bi * 32 + c) * H2 + 2 * i) * W2);
      const float2* p1 = (const float2*)(in + ((size_t)(bi * 32 + c) * H2 + 2 * i + 1) * W2);
      float2 r0 = p0[jg];
      float2 r1 = p1[jg];
      va = r0.x; vb = r0.y; vc = r1.x; vd = r1.y;
    }
    float ll = (va + vb + vc + vd) * 0.5f;
    float lh = (va - vb + vc - vd) * 0.5f;
    float hl = (va + vb - vc - vd) * 0.5f;
    float hh = (va - vb - vc + vd) * 0.5f;
    bf16x4_t q;
    q.x = (bf16_t)ll; q.y = (bf16_t)lh; q.z = (bf16_t)hl; q.w = (bf16_t)hh;
    *(bf16x4_t*)(&lds[j * 132 + c * 4]) = q;
    if (llout != nullptr && jok)
      llout[((size_t)(bi * 32 + c) * h + i) * w + jg] = ll;
  }
  __syncthreads();
  const size_t obase = ((size_t)bi * h + i) * w;
  for (int it = 0; it < 8; ++it) {
    int flat = it * 256 + tid;  // 2048 slots of 4 bf16
    int jj = flat >> 5;
    int c4 = flat & 31;
    if (j0 + jj < w) {
      bf16x4_t q = *(const bf16x4_t*)(&lds[jj * 132 + c4 * 4]);
      *(bf16x4_t*)(sub + ((obase + j0 + jj) << 7) + c4 * 4) = q;
    }
  }
}

// ---------------------------------------------------------------------------
// Fused conv 3x3 (pad1, 128->128ch, MFMA 32x32x16 bf16) + IDWT epilogue.
// Block: 8x16 spatial tile (M=128) x N=128, 4 waves (2x2), wave tile 64x64.
// A (halo) in LDS (46080 B -> 3 blocks/CU). B fragments loaded DIRECTLY from
// global (fragment-order repack, L2-resident, coalesced) -- no in-loop barriers.
// Epilogue: lanes 4c..4c+3 hold subbands ll,lh,hl,hh of channel c at one pixel;
// 2-stage shfl_xor butterfly = 4-pt Hadamard -> quadrant values a,b,c,d.
//   out[2gy + (q>>1)][2gx + (q&1)] = 0.5*butterfly + 0.5*nll + bias
// ---------------------------------------------------------------------------
__global__ __launch_bounds__(256, 3) void conv_idwt_kernel(
    const bf16_t* __restrict__ sub, const bf16_t* __restrict__ wt2,
    const float* __restrict__ nll, const float* __restrict__ bias,
    float* __restrict__ out, int h, int w) {
  __shared__ uint4 haloV[2880];            // 46080 B
  char* haloS = (char*)haloV;
  const int bi = blockIdx.z;
  const int y0 = blockIdx.y * 8;
  const int x0 = blockIdx.x * 16;
  const int tid = threadIdx.x;
  const size_t img_base = (size_t)bi * h * w;

  // ---- stage halo: 180 pixels x 16 chunks of 16B, zero-filled borders ----
  for (int it = 0; it < 12; ++it) {
    int flat = it * 256 + tid;
    int pix = flat >> 4;
    int ch = flat & 15;
    if (pix < 180) {
      int r = pix / 18;
      int c = pix - r * 18;
      int gy = y0 + r - 1;
      int gx = x0 + c - 1;
      uint4 v = make_uint4(0u, 0u, 0u, 0u);
      if ((unsigned)gy < (unsigned)h && (unsigned)gx < (unsigned)w)
        v = *(const uint4*)(sub + ((img_base + (size_t)gy * w + gx) << 7) + (ch << 3));
      *(uint4*)(haloS + (pix << 8) + ((ch ^ (pix & 7)) << 4)) = v;
    }
  }
  __syncthreads();

  const int lane = tid & 63;
  const int wav = tid >> 6;
  const int wr = wav >> 1;                 // wave row (0/1): spatial rows wr*4..+3
  const int wc = wav & 1;                  // wave col: oc base wc*64
  const int m = lane & 31;                 // A-operand m index
  const int hw_ = lane >> 5;               // half-wave: k offset hw_*8
  const int il = wr * 4 + (m >> 4);
  const int jl = m & 15;
  const int pixA = il * 18 + jl;
  const bf16_t* wlane = wt2 + (lane << 3);

  f32x16_t acc[2][2] = {};

  for (int t = 0; t < 9; ++t) {
    const int ky = t / 3;
    const int kx = t - ky * 3;
    const int pix0 = pixA + ky * 18 + kx;
    const int pix1 = pix0 + 36;            // mt=1: +2 spatial rows
    const int s0 = pix0 & 7;
    const int s1 = pix1 & 7;
#pragma unroll
    for (int hk = 0; hk < 2; ++hk) {       // 64-ic halves of the tap
      // B fragments straight from global (frag f = (t*2+hk)*16 + kc*4 + nt*2 + wc)
      const bf16_t* wbase = wlane + (((t * 2 + hk) * 16 + wc) << 9);
      bf16x8_t bfrag[4][2];
#pragma unroll
      for (int kc = 0; kc < 4; ++kc) {
        bfrag[kc][0] = *(const bf16x8_t*)(wbase + (kc << 11));
        bfrag[kc][1] = *(const bf16x8_t*)(wbase + (kc << 11) + 1024);
      }
      const char* hp0 = haloS + (pix0 << 8) + (hk << 7);
      const char* hp1 = haloS + (pix1 << 8) + (hk << 7);
#pragma unroll
      for (int kc = 0; kc < 4; ++kc) {
        const int cidx = kc * 2 + hw_;     // 16B chunk within the 64-ic half
        bf16x8_t a0 = *(const bf16x8_t*)(hp0 + ((cidx ^ s0) << 4));
        bf16x8_t a1 = *(const bf16x8_t*)(hp1 + ((cidx ^ s1) << 4));
        acc[0][0] = __builtin_amdgcn_mfma_f32_32x32x16_bf16(a0, bfrag[kc][0], acc[0][0], 0, 0, 0);
        acc[0][1] = __builtin_amdgcn_mfma_f32_32x32x16_bf16(a0, bfrag[kc][1], acc[0][1], 0, 0, 0);
        acc[1][0] = __builtin_amdgcn_mfma_f32_32x32x16_bf16(a1, bfrag[kc][0], acc[1][0], 0, 0, 0);
        acc[1][1] = __builtin_amdgcn_mfma_f32_32x32x16_bf16(a1, bfrag[kc][1], acc[1][1], 0, 0, 0);
      }
    }
  }

  // ---- fused IDWT epilogue ----
  // D layout (m74/m101): row = (reg&3)+8*(reg>>2)+4*hw_, col(oc) = lane&31
  const int oc0 = wc * 64 + (lane & 31);
  const int q = lane & 3;                  // subband index of this lane
  const int W2 = w * 2;
  const int H2 = h * 2;
#pragma unroll
  for (int nt = 0; nt < 2; ++nt) {
    const int ch = (oc0 + nt * 32) >> 2;   // output channel 0..31
    const float bv = (bias != nullptr) ? bias[ch] : 0.f;
    const float* nbase = (nll != nullptr) ? (nll + (size_t)(bi * 32 + ch) * h * w) : nullptr;
    float* obase = out + (size_t)(bi * 32 + ch) * H2 * W2;
#pragma unroll
    for (int mt = 0; mt < 2; ++mt) {
#pragma unroll
      for (int reg = 0; reg < 16; ++reg) {
        int row = (reg & 3) + ((reg >> 2) << 3) + (hw_ << 2);
        int p = wr * 64 + mt * 32 + row;
        int gy = y0 + (p >> 4);
        int gx = x0 + (p & 15);
        float v = acc[mt][nt][reg];
        // 4-pt Hadamard butterfly across subband lanes (same pixel per 4-group)
        float t1 = __shfl_xor(v, 1);
        float u = (q & 1) ? (t1 - v) : (v + t1);
        float t2 = __shfl_xor(u, 2);
        float r = (q & 2) ? (t2 - u) : (u + t2);
        bool ok = (gy < h) && (gx < w);
        float nv = 0.f;
        if (nbase != nullptr && ok) nv = nbase[(size_t)gy * w + gx];
        float res = 0.5f * r + 0.5f * nv + bv;
        if (ok)
          obase[(size_t)(2 * gy + (q >> 1)) * W2 + (2 * gx + (q & 1))] = res;
      }
    }
  }
}

// ---------------------------------------------------------------------------
// Workspace layout (bytes, peak 66,125,824 -- no y buffers, all fused):
//   wt2  @ 0           (294,912)
//   sub0 @ 294,912     (25,690,112)
//   sub1 @ 25,985,024  (6,422,528)
//   sub2 @ 32,407,552  (1,605,632)
//   ll0  @ 34,013,184  (12,845,056)
//   ll1  @ 46,858,240  (3,211,264)
//   nll2 @ 50,069,504  (3,211,264)
//   nll1 @ 53,280,768  (12,845,056)  -> end 66,125,824
// ---------------------------------------------------------------------------
extern "C" void kernel_launch(void* const* d_in, const int* in_sizes, int n_in,
                              void* d_out, int out_size, void* d_ws, size_t ws_size,
                              hipStream_t stream) {
  if (ws_size < 66125824u) return;

  const float* x = (const float*)d_in[0];
  const float* weight = (const float*)d_in[1];
  const float* bias = (const float*)d_in[2];
  float* out = (float*)d_out;
  char* ws = (char*)d_ws;

  bf16_t* wt2 = (bf16_t*)(ws);
  bf16_t* sub0 = (bf16_t*)(ws + 294912);
  bf16_t* sub1 = (bf16_t*)(ws + 25985024);
  bf16_t* sub2 = (bf16_t*)(ws + 32407552);
  float* ll0 = (float*)(ws + 34013184);
  float* ll1 = (float*)(ws + 46858240);
  float* nll2 = (float*)(ws + 50069504);
  float* nll1 = (float*)(ws + 53280768);

  repack_kernel<<<576, 256, 0, stream>>>(weight, wt2);

  // forward DWT chain
  dwt_kernel<<<dim3(2, 112, 8), 256, 0, stream>>>(x, sub0, ll0, 112, 112);
  dwt_kernel<<<dim3(1, 56, 8), 256, 0, stream>>>(ll0, sub1, ll1, 56, 56);
  dwt_kernel<<<dim3(1, 28, 8), 256, 0, stream>>>(ll1, sub2, nullptr, 28, 28);
  // fused conv+idwt, deepest level first
  conv_idwt_kernel<<<dim3(2, 4, 8), 256, 0, stream>>>(sub2, wt2, nullptr, nullptr, nll2, 28, 28);
  conv_idwt_kernel<<<dim3(4, 7, 8), 256, 0, stream>>>(sub1, wt2, nll2, nullptr, nll1, 56, 56);
  conv_idwt_kernel<<<dim3(7, 14, 8), 256, 0, stream>>>(sub0, wt2, nll1, bias, out, 112, 112);
}

// Round 2
// 256.142 us; speedup vs baseline: 1.1876x; 1.1876x over previous
//
#include <hip/hip_runtime.h>

typedef __bf16 bf16_t;
typedef __bf16 bf16x4_t __attribute__((ext_vector_type(4)));
typedef __bf16 bf16x8_t __attribute__((ext_vector_type(8)));
typedef float f32x16_t __attribute__((ext_vector_type(16)));

// ---------------------------------------------------------------------------
// Repack weight (oc, ic, ky, kx) fp32 -> bf16 in MFMA B-fragment order:
//   frag f = (((t*2+hk)*4 + kc)*2 + nt)*2 + wc
//   within frag: lane*8 + e  (lane 0..63, e 0..7)
//   lane maps to: oc = wc*64 + nt*32 + (lane&31); ic = (hk*8 + kc*2 + (lane>>5))*8 + e
// Each wave's fragment load is then a single contiguous, coalesced 1 KB read.
// ---------------------------------------------------------------------------
__global__ __launch_bounds__(256) void repack_kernel(const float* __restrict__ w,
                                                     bf16_t* __restrict__ wt2) {
  int o = blockIdx.x * 256 + threadIdx.x;  // 9*128*128 = 147456 exact
  int e = o & 7;
  int lane = (o >> 3) & 63;
  int f = o >> 9;
  int wc = f & 1;
  int nt = (f >> 1) & 1;
  int kc = (f >> 2) & 3;
  int hk = (f >> 4) & 1;
  int t = f >> 5;
  int oc = wc * 64 + nt * 32 + (lane & 31);
  int ic = (hk * 8 + kc * 2 + (lane >> 5)) * 8 + e;
  wt2[o] = (bf16_t)w[((size_t)oc * 128 + ic) * 9 + t];
}

// ---------------------------------------------------------------------------
// DWT: in fp32 (B,32,2h,2w) -> sub bf16 NHWC (B,h,w,128) ci=4c+q, ll fp32 (B,32,h,w)
// ---------------------------------------------------------------------------
__global__ __launch_bounds__(256) void dwt_kernel(const float* __restrict__ in,
                                                  bf16_t* __restrict__ sub,
                                                  float* __restrict__ llout,
                                                  int h, int w) {
  __shared__ __align__(16) bf16_t lds[64 * 132];
  const int bi = blockIdx.z;
  const int i = blockIdx.y;
  const int j0 = blockIdx.x * 64;
  const int tid = threadIdx.x;
  const int j = tid & 63;
  const int cg = tid >> 6;
  const int jg = j0 + j;
  const bool jok = jg < w;
  const int H2 = h * 2, W2 = w * 2;
  for (int c = cg; c < 32; c += 4) {
    float va = 0.f, vb = 0.f, vc = 0.f, vd = 0.f;
    if (jok) {
      const float2* p0 = (const float2*)(in + ((size_t)(bi * 32 + c) * H2 + 2 * i) * W2);
      const float2* p1 = (const float2*)(in + ((size_t)(bi * 32 + c) * H2 + 2 * i + 1) * W2);
      float2 r0 = p0[jg];
      float2 r1 = p1[jg];
      va = r0.x; vb = r0.y; vc = r1.x; vd = r1.y;
    }
    float ll = (va + vb + vc + vd) * 0.5f;
    float lh = (va - vb + vc - vd) * 0.5f;
    float hl = (va + vb - vc - vd) * 0.5f;
    float hh = (va - vb - vc + vd) * 0.5f;
    bf16x4_t q;
    q.x = (bf16_t)ll; q.y = (bf16_t)lh; q.z = (bf16_t)hl; q.w = (bf16_t)hh;
    *(bf16x4_t*)(&lds[j * 132 + c * 4]) = q;
    if (llout != nullptr && jok)
      llout[((size_t)(bi * 32 + c) * h + i) * w + jg] = ll;
  }
  __syncthreads();
  const size_t obase = ((size_t)bi * h + i) * w;
  for (int it = 0; it < 8; ++it) {
    int flat = it * 256 + tid;
    int jj = flat >> 5;
    int c4 = flat & 31;
    if (j0 + jj < w) {
      bf16x4_t q = *(const bf16x4_t*)(&lds[jj * 132 + c4 * 4]);
      *(bf16x4_t*)(sub + ((obase + j0 + jj) << 7) + c4 * 4) = q;
    }
  }
}

// ---------------------------------------------------------------------------
// Fused conv 3x3 (pad1, 128->128ch, MFMA 32x32x16 bf16) + IDWT epilogue.
// Block: 8x16 spatial tile (M=128) x N=128, 4 waves (2x2), wave tile 64x64.
// A (halo) in LDS (46080 B -> 3 blocks/CU). B fragments loaded DIRECTLY from
// global (fragment-order repack, L2-resident, coalesced) -- no in-loop barriers.
// Epilogue: stage raw acc into LDS [pix][oc] (reusing the halo buffer), then a
// cooperative read phase does the 4-pt Hadamard in-thread and stores coalesced
// float4s in NCHW. Zero shuffles, zero scattered stores.
// ---------------------------------------------------------------------------
__global__ __launch_bounds__(256, 3) void conv_idwt_kernel(
    const bf16_t* __restrict__ sub, const bf16_t* __restrict__ wt2,
    const float* __restrict__ nll, const float* __restrict__ bias,
    float* __restrict__ out, int h, int w) {
  __shared__ uint4 haloV[2880];            // 46080 B
  char* haloS = (char*)haloV;
  const int bi = blockIdx.z;
  const int y0 = blockIdx.y * 8;
  const int x0 = blockIdx.x * 16;
  const int tid = threadIdx.x;
  const size_t img_base = (size_t)bi * h * w;

  // ---- stage halo: 180 pixels x 16 chunks of 16B, zero-filled borders ----
  for (int it = 0; it < 12; ++it) {
    int flat = it * 256 + tid;
    int pix = flat >> 4;
    int ch = flat & 15;
    if (pix < 180) {
      int r = pix / 18;
      int c = pix - r * 18;
      int gy = y0 + r - 1;
      int gx = x0 + c - 1;
      uint4 v = make_uint4(0u, 0u, 0u, 0u);
      if ((unsigned)gy < (unsigned)h && (unsigned)gx < (unsigned)w)
        v = *(const uint4*)(sub + ((img_base + (size_t)gy * w + gx) << 7) + (ch << 3));
      *(uint4*)(haloS + (pix << 8) + ((ch ^ (pix & 7)) << 4)) = v;
    }
  }
  __syncthreads();

  const int lane = tid & 63;
  const int wav = tid >> 6;
  const int wr = wav >> 1;                 // wave row (0/1): spatial rows wr*4..+3
  const int wc = wav & 1;                  // wave col: oc base wc*64
  const int m = lane & 31;                 // A-operand m index
  const int hw_ = lane >> 5;               // half-wave: k offset hw_*8
  const int il = wr * 4 + (m >> 4);
  const int jl = m & 15;
  const int pixA = il * 18 + jl;
  const bf16_t* wlane = wt2 + (lane << 3);

  f32x16_t acc[2][2] = {};

  for (int t = 0; t < 9; ++t) {
    const int ky = t / 3;
    const int kx = t - ky * 3;
    const int pix0 = pixA + ky * 18 + kx;
    const int pix1 = pix0 + 36;            // mt=1: +2 spatial rows
    const int s0 = pix0 & 7;
    const int s1 = pix1 & 7;
#pragma unroll
    for (int hk = 0; hk < 2; ++hk) {       // 64-ic halves of the tap
      const bf16_t* wbase = wlane + (((t * 2 + hk) * 16 + wc) << 9);
      bf16x8_t bfrag[4][2];
#pragma unroll
      for (int kc = 0; kc < 4; ++kc) {
        bfrag[kc][0] = *(const bf16x8_t*)(wbase + (kc << 11));
        bfrag[kc][1] = *(const bf16x8_t*)(wbase + (kc << 11) + 1024);
      }
      const char* hp0 = haloS + (pix0 << 8) + (hk << 7);
      const char* hp1 = haloS + (pix1 << 8) + (hk << 7);
#pragma unroll
      for (int kc = 0; kc < 4; ++kc) {
        const int cidx = kc * 2 + hw_;
        bf16x8_t a0 = *(const bf16x8_t*)(hp0 + ((cidx ^ s0) << 4));
        bf16x8_t a1 = *(const bf16x8_t*)(hp1 + ((cidx ^ s1) << 4));
        acc[0][0] = __builtin_amdgcn_mfma_f32_32x32x16_bf16(a0, bfrag[kc][0], acc[0][0], 0, 0, 0);
        acc[0][1] = __builtin_amdgcn_mfma_f32_32x32x16_bf16(a0, bfrag[kc][1], acc[0][1], 0, 0, 0);
        acc[1][0] = __builtin_amdgcn_mfma_f32_32x32x16_bf16(a1, bfrag[kc][0], acc[1][0], 0, 0, 0);
        acc[1][1] = __builtin_amdgcn_mfma_f32_32x32x16_bf16(a1, bfrag[kc][1], acc[1][1], 0, 0, 0);
      }
    }
  }

  // ---- fused IDWT epilogue via LDS transpose ----
  // D layout (m74/m101): row = (reg&3)+8*(reg>>2)+4*hw_, col(oc) = lane&31
  //   conv pixel: gy_local = wr*4 + mt*2 + (row>>4), gx_local = row & 15
  float* scr = (float*)haloV;              // [64 pix][132] = 33792 B, reuses halo
  const int oc_lo = wc * 64 + (lane & 31);
  const int W2 = w * 2;
  const int H2 = h * 2;

#pragma unroll
  for (int mt = 0; mt < 2; ++mt) {
    __syncthreads();                       // halo reads / prior read-phase done
#pragma unroll
    for (int nt = 0; nt < 2; ++nt) {
      const int oc = oc_lo + nt * 32;
#pragma unroll
      for (int reg = 0; reg < 16; ++reg) {
        int row = (reg & 3) + ((reg >> 2) << 3) + (hw_ << 2);
        int cr = wr * 2 + (row >> 4);      // dense row slot 0..3 within this mt
        int gxl = row & 15;
        scr[(cr * 16 + gxl) * 132 + oc] = acc[mt][nt][reg];
      }
    }
    __syncthreads();
    // read phase: 32ch x 8 out-rows x 8 float4 = 2048 float4 -> 8 iters
#pragma unroll
    for (int it = 0; it < 8; ++it) {
      int idx = it * 256 + tid;
      int ox4 = idx & 7;
      int oyr = (idx >> 3) & 7;
      int ch = idx >> 6;                   // wave-uniform per iteration
      int cr = oyr >> 1;
      int dy = oyr & 1;
      int gy = y0 + (cr >> 1) * 4 + mt * 2 + (cr & 1);
      int gx = x0 + ox4 * 2;
      if (gy >= h || gx >= w) continue;
      int p0 = cr * 16 + ox4 * 2;
      float4 sa = *(const float4*)(&scr[p0 * 132 + ch * 4]);
      float4 sb = *(const float4*)(&scr[(p0 + 1) * 132 + ch * 4]);
      float sg = dy ? -1.f : 1.f;
      float e0 = sa.x + sa.y + sg * (sa.z + sa.w);
      float e1 = sa.x - sa.y + sg * (sa.z - sa.w);
      float e2 = sb.x + sb.y + sg * (sb.z + sb.w);
      float e3 = sb.x - sb.y + sg * (sb.z - sb.w);
      float n0 = 0.f, n1 = 0.f;
      if (nll != nullptr) {
        const float* np = nll + ((size_t)(bi * 32 + ch) * h + gy) * w + gx;
        float2 nv = *(const float2*)np;
        n0 = nv.x; n1 = nv.y;
      }
      float bv = (bias != nullptr) ? bias[ch] : 0.f;
      float4 o;
      o.x = 0.5f * e0 + 0.5f * n0 + bv;
      o.y = 0.5f * e1 + 0.5f * n0 + bv;
      o.z = 0.5f * e2 + 0.5f * n1 + bv;
      o.w = 0.5f * e3 + 0.5f * n1 + bv;
      float* op = out + ((size_t)(bi * 32 + ch) * H2 + 2 * gy + dy) * W2 + 2 * gx;
      *(float4*)op = o;
    }
  }
}

// ---------------------------------------------------------------------------
// Workspace layout (bytes, peak 66,125,824):
//   wt2  @ 0           (294,912)
//   sub0 @ 294,912     (25,690,112)
//   sub1 @ 25,985,024  (6,422,528)
//   sub2 @ 32,407,552  (1,605,632)
//   ll0  @ 34,013,184  (12,845,056)
//   ll1  @ 46,858,240  (3,211,264)
//   nll2 @ 50,069,504  (3,211,264)
//   nll1 @ 53,280,768  (12,845,056)  -> end 66,125,824
// ---------------------------------------------------------------------------
extern "C" void kernel_launch(void* const* d_in, const int* in_sizes, int n_in,
                              void* d_out, int out_size, void* d_ws, size_t ws_size,
                              hipStream_t stream) {
  if (ws_size < 66125824u) return;

  const float* x = (const float*)d_in[0];
  const float* weight = (const float*)d_in[1];
  const float* bias = (const float*)d_in[2];
  float* out = (float*)d_out;
  char* ws = (char*)d_ws;

  bf16_t* wt2 = (bf16_t*)(ws);
  bf16_t* sub0 = (bf16_t*)(ws + 294912);
  bf16_t* sub1 = (bf16_t*)(ws + 25985024);
  bf16_t* sub2 = (bf16_t*)(ws + 32407552);
  float* ll0 = (float*)(ws + 34013184);
  float* ll1 = (float*)(ws + 46858240);
  float* nll2 = (float*)(ws + 50069504);
  float* nll1 = (float*)(ws + 53280768);

  repack_kernel<<<576, 256, 0, stream>>>(weight, wt2);

  // forward DWT chain
  dwt_kernel<<<dim3(2, 112, 8), 256, 0, stream>>>(x, sub0, ll0, 112, 112);
  dwt_kernel<<<dim3(1, 56, 8), 256, 0, stream>>>(ll0, sub1, ll1, 56, 56);
  dwt_kernel<<<dim3(1, 28, 8), 256, 0, stream>>>(ll1, sub2, nullptr, 28, 28);
  // fused conv+idwt, deepest level first
  conv_idwt_kernel<<<dim3(2, 4, 8), 256, 0, stream>>>(sub2, wt2, nullptr, nullptr, nll2, 28, 28);
  conv_idwt_kernel<<<dim3(4, 7, 8), 256, 0, stream>>>(sub1, wt2, nll2, nullptr, nll1, 56, 56);
  conv_idwt_kernel<<<dim3(7, 14, 8), 256, 0, stream>>>(sub0, wt2, nll1, bias, out, 112, 112);
}

// Round 3
// 235.173 us; speedup vs baseline: 1.2935x; 1.0892x over previous
//
#include <hip/hip_runtime.h>

typedef __bf16 bf16_t;
typedef __bf16 bf16x4_t __attribute__((ext_vector_type(4)));
typedef __bf16 bf16x8_t __attribute__((ext_vector_type(8)));
typedef float f32x16_t __attribute__((ext_vector_type(16)));

// ---------------------------------------------------------------------------
// Repack weight (oc, ic, ky, kx) fp32 -> bf16 in MFMA B-fragment order:
//   frag f = ((th*4 + kc)*2 + nt)*2 + wc,  th = t*2+hk
//   within frag: lane*8 + e  (lane 0..63, e 0..7)
//   lane maps to: oc = wc*64 + nt*32 + (lane&31); ic = (hk*8 + kc*2 + (lane>>5))*8 + e
// ---------------------------------------------------------------------------
__global__ __launch_bounds__(256) void repack_kernel(const float* __restrict__ w,
                                                     bf16_t* __restrict__ wt2) {
  int o = blockIdx.x * 256 + threadIdx.x;  // 9*128*128 = 147456 exact
  int e = o & 7;
  int lane = (o >> 3) & 63;
  int f = o >> 9;
  int wc = f & 1;
  int nt = (f >> 1) & 1;
  int kc = (f >> 2) & 3;
  int hk = (f >> 4) & 1;
  int t = f >> 5;
  int oc = wc * 64 + nt * 32 + (lane & 31);
  int ic = (hk * 8 + kc * 2 + (lane >> 5)) * 8 + e;
  wt2[o] = (bf16_t)w[((size_t)oc * 128 + ic) * 9 + t];
}

// ---------------------------------------------------------------------------
// DWT: in fp32 (B,32,2h,2w) -> sub bf16 NHWC (B,h,w,128) ci=4c+q, ll fp32 (B,32,h,w)
// ---------------------------------------------------------------------------
__global__ __launch_bounds__(256) void dwt_kernel(const float* __restrict__ in,
                                                  bf16_t* __restrict__ sub,
                                                  float* __restrict__ llout,
                                                  int h, int w) {
  __shared__ __align__(16) bf16_t lds[64 * 132];
  const int bi = blockIdx.z;
  const int i = blockIdx.y;
  const int j0 = blockIdx.x * 64;
  const int tid = threadIdx.x;
  const int j = tid & 63;
  const int cg = tid >> 6;
  const int jg = j0 + j;
  const bool jok = jg < w;
  const int H2 = h * 2, W2 = w * 2;
  for (int c = cg; c < 32; c += 4) {
    float va = 0.f, vb = 0.f, vc = 0.f, vd = 0.f;
    if (jok) {
      const float2* p0 = (const float2*)(in + ((size_t)(bi * 32 + c) * H2 + 2 * i) * W2);
      const float2* p1 = (const float2*)(in + ((size_t)(bi * 32 + c) * H2 + 2 * i + 1) * W2);
      float2 r0 = p0[jg];
      float2 r1 = p1[jg];
      va = r0.x; vb = r0.y; vc = r1.x; vd = r1.y;
    }
    float ll = (va + vb + vc + vd) * 0.5f;
    float lh = (va - vb + vc - vd) * 0.5f;
    float hl = (va + vb - vc - vd) * 0.5f;
    float hh = (va - vb - vc + vd) * 0.5f;
    bf16x4_t q;
    q.x = (bf16_t)ll; q.y = (bf16_t)lh; q.z = (bf16_t)hl; q.w = (bf16_t)hh;
    *(bf16x4_t*)(&lds[j * 132 + c * 4]) = q;
    if (llout != nullptr && jok)
      llout[((size_t)(bi * 32 + c) * h + i) * w + jg] = ll;
  }
  __syncthreads();
  const size_t obase = ((size_t)bi * h + i) * w;
  for (int it = 0; it < 8; ++it) {
    int flat = it * 256 + tid;
    int jj = flat >> 5;
    int c4 = flat & 31;
    if (j0 + jj < w) {
      bf16x4_t q = *(const bf16x4_t*)(&lds[jj * 132 + c4 * 4]);
      *(bf16x4_t*)(sub + ((obase + j0 + jj) << 7) + c4 * 4) = q;
    }
  }
}

// ---------------------------------------------------------------------------
// Fused conv 3x3 (pad1, 128->128ch, MFMA 32x32x16 bf16) + IDWT epilogue.
// Block: 8x16 spatial tile (M=128) x N=128, 4 waves (2x2), wave tile 64x64.
// A (halo) in LDS (46080 B -> 3 blocks/CU). B fragments from global
// (fragment-order repack, L2-resident) with fully-unrolled 18-phase loop and
// explicit ping-pong register double-buffer: phase t+1's 8 loads issue before
// phase t's MFMAs so L2 latency hides under compute.
// Epilogue: LDS transpose then coalesced NCHW float4 stores; optional
// nll (same res) and nllup (half res, x0.5 -- IDWT-linearity fold of the
// deeper level) and bias.
// ---------------------------------------------------------------------------
__device__ __forceinline__ void conv_idwt_tile(
    const bf16_t* __restrict__ sub, const bf16_t* __restrict__ wt2,
    const float* __restrict__ nll, const float* __restrict__ nllup,
    const float* __restrict__ bias, float* __restrict__ out,
    int h, int w, int bi, int y0, int x0, uint4* haloV) {
  char* haloS = (char*)haloV;
  const int tid = threadIdx.x;
  const size_t img_base = (size_t)bi * h * w;

  // ---- stage halo: 180 pixels x 16 chunks of 16B, zero-filled borders ----
  for (int it = 0; it < 12; ++it) {
    int flat = it * 256 + tid;
    int pix = flat >> 4;
    int ch = flat & 15;
    if (pix < 180) {
      int r = pix / 18;
      int c = pix - r * 18;
      int gy = y0 + r - 1;
      int gx = x0 + c - 1;
      uint4 v = make_uint4(0u, 0u, 0u, 0u);
      if ((unsigned)gy < (unsigned)h && (unsigned)gx < (unsigned)w)
        v = *(const uint4*)(sub + ((img_base + (size_t)gy * w + gx) << 7) + (ch << 3));
      *(uint4*)(haloS + (pix << 8) + ((ch ^ (pix & 7)) << 4)) = v;
    }
  }
  __syncthreads();

  const int lane = tid & 63;
  const int wav = tid >> 6;
  const int wr = wav >> 1;                 // wave row (0/1): spatial rows wr*4..+3
  const int wc = wav & 1;                  // wave col: oc base wc*64
  const int m = lane & 31;                 // A-operand m index
  const int hw_ = lane >> 5;               // half-wave: k offset hw_*8
  const int il = wr * 4 + (m >> 4);
  const int jl = m & 15;
  const int pixA = il * 18 + jl;
  const bf16_t* wlane = wt2 + (lane << 3) + (wc << 9);

  f32x16_t acc[2][2] = {};
  bf16x8_t bb[2][8];                       // ping-pong B fragments

#pragma unroll
  for (int i = 0; i < 4; ++i) {            // preload phase 0
    bb[0][2 * i] = *(const bf16x8_t*)(wlane + (i << 11));
    bb[0][2 * i + 1] = *(const bf16x8_t*)(wlane + (i << 11) + 1024);
  }

#pragma unroll
  for (int th = 0; th < 18; ++th) {        // th = t*2 + hk
    const int t = th >> 1;
    const int hk = th & 1;
    const int ky = t / 3;
    const int kx = t - ky * 3;
    const int cur = th & 1 ? 1 : 0;        // compile-time after unroll
    const int nxt = cur ^ 1;
    if (th < 17) {
      const bf16_t* wb = wlane + ((th + 1) << 13);
#pragma unroll
      for (int i = 0; i < 4; ++i) {
        bb[nxt][2 * i] = *(const bf16x8_t*)(wb + (i << 11));
        bb[nxt][2 * i + 1] = *(const bf16x8_t*)(wb + (i << 11) + 1024);
      }
    }
    const int pix0 = pixA + ky * 18 + kx;
    const int pix1 = pix0 + 36;            // mt=1: +2 spatial rows
    const int s0 = pix0 & 7;
    const int s1 = pix1 & 7;
    const char* hp0 = haloS + (pix0 << 8) + (hk << 7);
    const char* hp1 = haloS + (pix1 << 8) + (hk << 7);
#pragma unroll
    for (int kc = 0; kc < 4; ++kc) {
      const int cidx = kc * 2 + hw_;
      bf16x8_t a0 = *(const bf16x8_t*)(hp0 + ((cidx ^ s0) << 4));
      bf16x8_t a1 = *(const bf16x8_t*)(hp1 + ((cidx ^ s1) << 4));
      acc[0][0] = __builtin_amdgcn_mfma_f32_32x32x16_bf16(a0, bb[cur][2 * kc], acc[0][0], 0, 0, 0);
      acc[0][1] = __builtin_amdgcn_mfma_f32_32x32x16_bf16(a0, bb[cur][2 * kc + 1], acc[0][1], 0, 0, 0);
      acc[1][0] = __builtin_amdgcn_mfma_f32_32x32x16_bf16(a1, bb[cur][2 * kc], acc[1][0], 0, 0, 0);
      acc[1][1] = __builtin_amdgcn_mfma_f32_32x32x16_bf16(a1, bb[cur][2 * kc + 1], acc[1][1], 0, 0, 0);
    }
  }

  // ---- fused IDWT epilogue via LDS transpose ----
  // D layout (m74/m101): row = (reg&3)+8*(reg>>2)+4*hw_, col(oc) = lane&31
  float* scr = (float*)haloV;              // [64 pix][132] = 33792 B, reuses halo
  const int oc_lo = wc * 64 + (lane & 31);
  const int W2 = w * 2;
  const int H2 = h * 2;
  const int hu = h >> 1, wu = w >> 1;

#pragma unroll
  for (int mt = 0; mt < 2; ++mt) {
    __syncthreads();                       // halo reads / prior read-phase done
#pragma unroll
    for (int nt = 0; nt < 2; ++nt) {
      const int oc = oc_lo + nt * 32;
#pragma unroll
      for (int reg = 0; reg < 16; ++reg) {
        int row = (reg & 3) + ((reg >> 2) << 3) + (hw_ << 2);
        int cr = wr * 2 + (row >> 4);      // dense row slot 0..3 within this mt
        int gxl = row & 15;
        scr[(cr * 16 + gxl) * 132 + oc] = acc[mt][nt][reg];
      }
    }
    __syncthreads();
    // read phase: 32ch x 8 out-rows x 8 float4 = 2048 float4 -> 8 iters
#pragma unroll
    for (int it = 0; it < 8; ++it) {
      int idx = it * 256 + tid;
      int ox4 = idx & 7;
      int oyr = (idx >> 3) & 7;
      int ch = idx >> 6;                   // wave-uniform per iteration
      int cr = oyr >> 1;
      int dy = oyr & 1;
      int gy = y0 + (cr >> 1) * 4 + mt * 2 + (cr & 1);
      int gx = x0 + ox4 * 2;
      if (gy >= h || gx >= w) continue;
      int p0 = cr * 16 + ox4 * 2;
      float4 sa = *(const float4*)(&scr[p0 * 132 + ch * 4]);
      float4 sb = *(const float4*)(&scr[(p0 + 1) * 132 + ch * 4]);
      float sg = dy ? -1.f : 1.f;
      float e0 = sa.x + sa.y + sg * (sa.z + sa.w);
      float e1 = sa.x - sa.y + sg * (sa.z - sa.w);
      float e2 = sb.x + sb.y + sg * (sb.z + sb.w);
      float e3 = sb.x - sb.y + sg * (sb.z - sb.w);
      float n0 = 0.f, n1 = 0.f;
      if (nll != nullptr) {
        const float* np = nll + ((size_t)(bi * 32 + ch) * h + gy) * w + gx;
        float2 nv = *(const float2*)np;
        n0 = nv.x; n1 = nv.y;
      }
      if (nllup != nullptr) {              // deeper level, half res, IDWT-linear fold
        float u = nllup[((size_t)(bi * 32 + ch) * hu + (gy >> 1)) * wu + (gx >> 1)];
        n0 += 0.5f * u;
        n1 += 0.5f * u;
      }
      float bv = (bias != nullptr) ? bias[ch] : 0.f;
      float4 o;
      o.x = 0.5f * e0 + 0.5f * n0 + bv;
      o.y = 0.5f * e1 + 0.5f * n0 + bv;
      o.z = 0.5f * e2 + 0.5f * n1 + bv;
      o.w = 0.5f * e3 + 0.5f * n1 + bv;
      float* op = out + ((size_t)(bi * 32 + ch) * H2 + 2 * gy + dy) * W2 + 2 * gx;
      *(float4*)op = o;
    }
  }
}

// conv0: 3D grid, has nll (level-1 raw idwt) + nllup (level-2 idwt) + bias
__global__ __launch_bounds__(256, 3) void conv_idwt_kernel(
    const bf16_t* __restrict__ sub, const bf16_t* __restrict__ wt2,
    const float* __restrict__ nll, const float* __restrict__ nllup,
    const float* __restrict__ bias, float* __restrict__ out, int h, int w) {
  __shared__ uint4 haloV[2880];            // 46080 B
  conv_idwt_tile(sub, wt2, nll, nllup, bias, out, h, w,
                 blockIdx.z, blockIdx.y * 8, blockIdx.x * 16, haloV);
}

// conv1+conv2 merged into one dispatch (IDWT linearity makes them independent):
// blocks [0,224): level 1 (56x56), blocks [224,288): level 2 (28x28).
__global__ __launch_bounds__(256, 3) void conv12_kernel(
    const bf16_t* __restrict__ sub1, const bf16_t* __restrict__ sub2,
    const bf16_t* __restrict__ wt2, float* __restrict__ nll1raw,
    float* __restrict__ nll2) {
  __shared__ uint4 haloV[2880];            // 46080 B
  const int B = blockIdx.x;
  const bf16_t* sub;
  float* outp;
  int hh, bi, by, bx;
  if (B < 224) {                           // level 1: old grid (4,7,8)
    bx = B & 3;
    int r = B >> 2;
    by = r % 7;
    bi = r / 7;
    sub = sub1; outp = nll1raw; hh = 56;
  } else {                                 // level 2: old grid (2,4,8)
    int lb = B - 224;
    bx = lb & 1;
    int r = lb >> 1;
    by = r & 3;
    bi = r >> 2;
    sub = sub2; outp = nll2; hh = 28;
  }
  conv_idwt_tile(sub, wt2, nullptr, nullptr, nullptr, outp, hh, hh,
                 bi, by * 8, bx * 16, haloV);
}

// ---------------------------------------------------------------------------
// Workspace layout (bytes, peak 66,125,824):
//   wt2  @ 0           (294,912)
//   sub0 @ 294,912     (25,690,112)
//   sub1 @ 25,985,024  (6,422,528)
//   sub2 @ 32,407,552  (1,605,632)
//   ll0  @ 34,013,184  (12,845,056)
//   ll1  @ 46,858,240  (3,211,264)
//   nll2 @ 50,069,504  (3,211,264)
//   nll1 @ 53,280,768  (12,845,056)  -> end 66,125,824
// ---------------------------------------------------------------------------
extern "C" void kernel_launch(void* const* d_in, const int* in_sizes, int n_in,
                              void* d_out, int out_size, void* d_ws, size_t ws_size,
                              hipStream_t stream) {
  if (ws_size < 66125824u) return;

  const float* x = (const float*)d_in[0];
  const float* weight = (const float*)d_in[1];
  const float* bias = (const float*)d_in[2];
  float* out = (float*)d_out;
  char* ws = (char*)d_ws;

  bf16_t* wt2 = (bf16_t*)(ws);
  bf16_t* sub0 = (bf16_t*)(ws + 294912);
  bf16_t* sub1 = (bf16_t*)(ws + 25985024);
  bf16_t* sub2 = (bf16_t*)(ws + 32407552);
  float* ll0 = (float*)(ws + 34013184);
  float* ll1 = (float*)(ws + 46858240);
  float* nll2 = (float*)(ws + 50069504);
  float* nll1 = (float*)(ws + 53280768);

  repack_kernel<<<576, 256, 0, stream>>>(weight, wt2);

  // forward DWT chain
  dwt_kernel<<<dim3(2, 112, 8), 256, 0, stream>>>(x, sub0, ll0, 112, 112);
  dwt_kernel<<<dim3(1, 56, 8), 256, 0, stream>>>(ll0, sub1, ll1, 56, 56);
  dwt_kernel<<<dim3(1, 28, 8), 256, 0, stream>>>(ll1, sub2, nullptr, 28, 28);
  // levels 1+2 conv+idwt in ONE dispatch (independent via linearity)
  conv12_kernel<<<288, 256, 0, stream>>>(sub1, sub2, wt2, nll1, nll2);
  // level 0 conv+idwt consumes nll1raw + 0.5*up(nll2), adds bias
  conv_idwt_kernel<<<dim3(7, 14, 8), 256, 0, stream>>>(sub0, wt2, nll1, nll2, bias, out, 112, 112);
}